// Round 1
// baseline (513.045 us; speedup 1.0000x reference)
//
#include <hip/hip_runtime.h>
#include <math.h>

#define BATCH 16
#define NHEAD 32
#define HDIM 128
#define HIDDEN 4096
#define BS 16
#define MB 128
#define EPS 1e-6f
#define SPLIT 128   // one split per KV-cache page (16 tokens); grid covers max pages

// ws layout (floats):
//   pm:   [B][H][SPLIT]            at 0
//   pl:   [B][H][SPLIT]            at PL_OFF
//   pacc: [B][H][SPLIT][HDIM]      at PA_OFF
#define PCOUNT (BATCH * NHEAD * SPLIT)
#define PL_OFF PCOUNT
#define PA_OFF (2 * PCOUNT)

// One block = one (batch, page). Streams the whole 256 KB K page + 256 KB V page
// contiguously, computing ALL 32 heads. Thread t, sub-iter i reads float4 slot
// (t + 256*i) of each 16 KB token row; half-wave w = t>>5 at sub-iter i owns head
// w + 8*i, lanes hold dims 4*lane..4*lane+3. RMSNorm is computed inline (x/w are
// L2-resident; redundant per-block recompute is ~2 us total).
__global__ __launch_bounds__(256) void attn_page_kernel(
    const float* __restrict__ x, const float* __restrict__ rw,
    const float* __restrict__ kc, const float* __restrict__ vc,
    const int* __restrict__ bt, const int* __restrict__ cl,
    float* __restrict__ pm, float* __restrict__ pl, float* __restrict__ pacc) {
    const int si = blockIdx.x;          // page index within sequence
    const int b = blockIdx.y;
    const int L = cl[b];
    const int nsp = (L + BS - 1) >> 4;  // busy pages for this sequence
    if (si >= nsp) return;              // uniform early-exit (before any barrier)
    const int nt = min(BS, L - (si << 4));
    const int tid = threadIdx.x;
    const int hw = tid >> 5;            // half-wave 0..7
    const int lane = tid & 31;

    // ---- inline RMSNorm: build q fragments for float4 slots tid + 256*i ----
    const float4* xr = (const float4*)(x + (size_t)b * HIDDEN);
    const float4* wr = (const float4*)rw;
    float4 qf[4];
    float ss = 0.f;
#pragma unroll
    for (int i = 0; i < 4; i++) {
        float4 v = xr[tid + 256 * i];
        qf[i] = v;
        ss += v.x * v.x + v.y * v.y + v.z * v.z + v.w * v.w;
    }
#pragma unroll
    for (int m = 32; m >= 1; m >>= 1) ss += __shfl_xor(ss, m, 64);
    __shared__ float red[4];
    if ((tid & 63) == 0) red[tid >> 6] = ss;
    __syncthreads();
    const float rstd = rsqrtf((red[0] + red[1] + red[2] + red[3]) * (1.0f / HIDDEN) + EPS);
#pragma unroll
    for (int i = 0; i < 4; i++) {
        float4 wv = wr[tid + 256 * i];
        qf[i].x *= rstd * wv.x;
        qf[i].y *= rstd * wv.y;
        qf[i].z *= rstd * wv.z;
        qf[i].w *= rstd * wv.w;
    }

    // ---- stream one KV page (16 token rows of 16 KB each, contiguous) ----
    const int pg = bt[b * MB + si];     // wave-uniform scalar
    const float4* kb = (const float4*)(kc + (size_t)pg * (BS * HIDDEN));
    const float4* vb = (const float4*)(vc + (size_t)pg * (BS * HIDDEN));

    const float scale = 0.08838834764831845f;  // 1/sqrt(128)
    float m0[4], l0[4];
    float4 acc[4];
#pragma unroll
    for (int i = 0; i < 4; i++) {
        m0[i] = -INFINITY;
        l0[i] = 0.f;
        acc[i] = make_float4(0.f, 0.f, 0.f, 0.f);
    }

    for (int t = 0; t < nt; ++t) {
        const float4* krow = kb + (size_t)t * (HIDDEN / 4);
        const float4* vrow = vb + (size_t)t * (HIDDEN / 4);
        float4 k4[4], v4[4];
#pragma unroll
        for (int i = 0; i < 4; i++) {  // issue all 8 loads up-front (8 KB/wave in flight)
            k4[i] = krow[tid + 256 * i];
            v4[i] = vrow[tid + 256 * i];
        }
#pragma unroll
        for (int i = 0; i < 4; i++) {  // 4 independent head-chains per thread
            float d = k4[i].x * qf[i].x + k4[i].y * qf[i].y + k4[i].z * qf[i].z +
                      k4[i].w * qf[i].w;
#pragma unroll
            for (int msk = 16; msk >= 1; msk >>= 1) d += __shfl_xor(d, msk, 64);
            float sc = d * scale;
            float mn = fmaxf(m0[i], sc);
            float al = __expf(m0[i] - mn);  // first token: exp(-inf)=0
            float p = __expf(sc - mn);
            l0[i] = l0[i] * al + p;
            acc[i].x = acc[i].x * al + p * v4[i].x;
            acc[i].y = acc[i].y * al + p * v4[i].y;
            acc[i].z = acc[i].z * al + p * v4[i].z;
            acc[i].w = acc[i].w * al + p * v4[i].w;
            m0[i] = mn;
        }
    }

    // ---- write partials: head h = hw + 8*i; coalesced float4 per half-wave ----
#pragma unroll
    for (int i = 0; i < 4; i++) {
        const int h = hw + 8 * i;
        const size_t pb = (size_t)(b * NHEAD + h) * SPLIT + si;
        if (lane == 0) {
            pm[pb] = m0[i];
            pl[pb] = l0[i];
        }
        *(float4*)(pacc + pb * HDIM + 4 * lane) = acc[i];
    }
}

// ---- combine busy pages + residual; only reads si < nsp (no neutral writes needed) ----
__global__ __launch_bounds__(128) void attn_combine_kernel(
    const float* __restrict__ pm, const float* __restrict__ pl,
    const float* __restrict__ pacc, const float* __restrict__ resid,
    const int* __restrict__ cl, float* __restrict__ out) {
    const int h = blockIdx.x;
    const int b = blockIdx.y;
    const int tid = threadIdx.x;
    const int L = cl[b];
    const int nsp = (L + BS - 1) >> 4;
    const size_t pb0 = (size_t)(b * NHEAD + h) * SPLIT;

    float M = -INFINITY;
    for (int si = 0; si < nsp; ++si) M = fmaxf(M, pm[pb0 + si]);
    float Ls = 0.f, A = 0.f;
#pragma unroll 4
    for (int si = 0; si < nsp; ++si) {
        float sc = __expf(pm[pb0 + si] - M);
        Ls += pl[pb0 + si] * sc;
        A += pacc[(pb0 + si) * HDIM + tid] * sc;
    }
    const size_t oi = (size_t)b * HIDDEN + h * HDIM + tid;
    out[oi] = resid[oi] + A / Ls;
}

extern "C" void kernel_launch(void* const* d_in, const int* in_sizes, int n_in,
                              void* d_out, int out_size, void* d_ws, size_t ws_size,
                              hipStream_t stream) {
    const float* hs = (const float*)d_in[0];
    const float* kc = (const float*)d_in[1];
    const float* vc = (const float*)d_in[2];
    const int* bt = (const int*)d_in[3];
    const int* cl = (const int*)d_in[4];
    const float* rw = (const float*)d_in[5];
    float* out = (float*)d_out;
    float* ws = (float*)d_ws;
    float* pm = ws;
    float* pl = ws + PL_OFF;
    float* pacc = ws + PA_OFF;

    attn_page_kernel<<<dim3(SPLIT, BATCH), 256, 0, stream>>>(hs, rw, kc, vc, bt, cl,
                                                             pm, pl, pacc);
    attn_combine_kernel<<<dim3(NHEAD, BATCH), 128, 0, stream>>>(pm, pl, pacc, hs, cl, out);
}